// Round 1
// baseline (5373.667 us; speedup 1.0000x reference)
//
#include <hip/hip_runtime.h>

// LSTM encoder: V=32000 E=512 U=1024 L=2, B=64 T=256.
// Strategy: fp16 MFMA (f32 accum) everywhere; bulk input projections as tiled
// GEMMs; sequential scan as 512 small per-step kernels (baseline round).

typedef _Float16 f16;
typedef _Float16 f16x8 __attribute__((ext_vector_type(8)));
typedef _Float16 f16x4 __attribute__((ext_vector_type(4)));
typedef float f32x4 __attribute__((ext_vector_type(4)));

__device__ __forceinline__ f32x4 mfma16x32(f16x8 a, f16x8 b, f32x4 c) {
  return __builtin_amdgcn_mfma_f32_16x16x32_f16(a, b, c, 0, 0, 0);
}

__device__ __forceinline__ void gl_lds16(const void* g, void* l) {
  __builtin_amdgcn_global_load_lds(
      (const __attribute__((address_space(1))) void*)g,
      (__attribute__((address_space(3))) void*)l, 16, 0, 0);
}

// ---------- transpose + cast: D[n][k] = (f16)S[k][n], K%64==0, N%64==0 ----------
__global__ __launch_bounds__(256) void k_transpose_f16(
    const float* __restrict__ S, f16* __restrict__ D, int K, int N) {
  __shared__ float tile[64][65];
  int nk = K >> 6;
  int k0 = (blockIdx.x % nk) << 6;
  int n0 = (blockIdx.x / nk) << 6;
  int tc = threadIdx.x & 63;
  int tq = threadIdx.x >> 6;
#pragma unroll
  for (int r = 0; r < 16; ++r) {
    int kk = tq * 16 + r;
    tile[kk][tc] = S[(size_t)(k0 + kk) * N + (n0 + tc)];
  }
  __syncthreads();
#pragma unroll
  for (int r = 0; r < 16; ++r) {
    int nn = tq * 16 + r;
    D[(size_t)(n0 + nn) * K + (k0 + tc)] = (f16)tile[tc][nn];
  }
}

// ---------- embedding lookup -> fp16 A0[m][512], row m = t*64 + b ----------
__global__ __launch_bounds__(256) void k_embed_f16(
    const int* __restrict__ tok, const float* __restrict__ emb,
    f16* __restrict__ A0) {
  int i = blockIdx.x * 256 + threadIdx.x;  // 16384 rows * 128 float4
  int m = i >> 7;
  int e = (i & 127) << 2;
  int t = m >> 6, b = m & 63;
  int tk = tok[b * 256 + t];
  const float4 v = *(const float4*)(emb + (size_t)tk * 512 + e);
  f16x4 o = {(f16)v.x, (f16)v.y, (f16)v.z, (f16)v.w};
  *(f16x4*)(A0 + (size_t)m * 512 + e) = o;
}

// ---------- C[m][n] = (f16)(sum_k A[m][k]*Bt[n][k] + bias[n]) ----------
// 128x128 tile, BK=32, 4 waves each 64x64, double-buffered global_load_lds.
__global__ __launch_bounds__(256) void k_gemm_f16(
    const f16* __restrict__ A, const f16* __restrict__ Bt,
    const float* __restrict__ bias, f16* __restrict__ C,
    int M, int N, int K) {
  __shared__ f16 sA[2][128 * 32];
  __shared__ f16 sB[2][128 * 32];
  const int tid = threadIdx.x, lane = tid & 63, w = tid >> 6;
  const int mb = M >> 7;
  const int bm = blockIdx.x % mb, bn = blockIdx.x / mb;
  const int am0 = bm << 7, bn0 = bn << 7;
  const int wm = w >> 1, wn = w & 1;
  const int srow = lane >> 2, sch = lane & 3;

  f32x4 acc[4][4] = {};
  const int NT = K >> 5;
  int cur = 0;

  auto stage = [&](int kt, int buf) {
#pragma unroll
    for (int q2 = 0; q2 < 2; ++q2) {
      int q = w * 2 + q2;
      int row = q * 16 + srow;
      const f16* ga = A + (size_t)(am0 + row) * K + kt * 32 + sch * 8;
      const f16* gb = Bt + (size_t)(bn0 + row) * K + kt * 32 + sch * 8;
      gl_lds16(ga, (char*)&sA[buf][0] + q * 1024);
      gl_lds16(gb, (char*)&sB[buf][0] + q * 1024);
    }
  };

  stage(0, 0);
  __syncthreads();
  for (int kt = 0; kt < NT; ++kt) {
    if (kt + 1 < NT) stage(kt + 1, cur ^ 1);
    const f16* pa = &sA[cur][(wm * 64 + (lane & 15)) * 32 + (lane >> 4) * 8];
    const f16* pb = &sB[cur][(wn * 64 + (lane & 15)) * 32 + (lane >> 4) * 8];
    f16x8 av[4], bv[4];
#pragma unroll
    for (int mf = 0; mf < 4; ++mf) av[mf] = *(const f16x8*)(pa + mf * 512);
#pragma unroll
    for (int nf = 0; nf < 4; ++nf) bv[nf] = *(const f16x8*)(pb + nf * 512);
#pragma unroll
    for (int mf = 0; mf < 4; ++mf)
#pragma unroll
      for (int nf = 0; nf < 4; ++nf)
        acc[mf][nf] = mfma16x32(av[mf], bv[nf], acc[mf][nf]);
    __syncthreads();
    cur ^= 1;
  }

#pragma unroll
  for (int mf = 0; mf < 4; ++mf)
#pragma unroll
    for (int nf = 0; nf < 4; ++nf) {
      int col = bn0 + wn * 64 + nf * 16 + (lane & 15);
      float bs = bias[col];
#pragma unroll
      for (int r = 0; r < 4; ++r) {
        int row = am0 + wm * 64 + mf * 16 + (lane >> 4) * 4 + r;
        C[(size_t)row * N + col] = (f16)(acc[mf][nf][r] + bs);
      }
    }
}

// ---------- one LSTM time step ----------
// z[64,4096] = XZ[t] + h @ U ; gates ; writes new h (fp16), c (f32), outputs.
// Grid: 256 WGs; WG owns units [4*bid, 4*bid+4) across all 4 gates (16 cols).
// 4 waves split K=1024 into 256-chunks; partials reduced through LDS.
__device__ __forceinline__ float sigmoidf_(float x) {
  return 1.0f / (1.0f + expf(-x));
}

__global__ __launch_bounds__(256) void k_lstm_step(
    const f16* __restrict__ XZ, const f16* __restrict__ Ut,
    const f16* __restrict__ hin, f16* __restrict__ hout,
    float* __restrict__ cst, f16* __restrict__ A1,
    float* __restrict__ outx, float* __restrict__ outh,
    float* __restrict__ outc, int t) {
  __shared__ float zred[4 * 64 * 16];
  const int tid = threadIdx.x, lane = tid & 63, w = tid >> 6;
  const int u0 = blockIdx.x * 4;
  const int j = lane & 15, kg = lane >> 4;
  const int n = (j >> 2) * 1024 + u0 + (j & 3);  // gate = j>>2, unit = u0+(j&3)

  // B fragments (U^T rows) straight from global: 8 k-tiles of this wave's K/4.
  const f16* bp = Ut + (size_t)n * 1024 + w * 256 + kg * 8;
  f16x8 bv[8];
#pragma unroll
  for (int kt = 0; kt < 8; ++kt) bv[kt] = *(const f16x8*)(bp + kt * 32);

  // A fragments (h rows) straight from global; each element used once.
  const f16* ap = hin + (size_t)j * 1024 + w * 256 + kg * 8;
  f32x4 acc[4] = {};
#pragma unroll
  for (int kt = 0; kt < 8; ++kt) {
#pragma unroll
    for (int mf = 0; mf < 4; ++mf) {
      f16x8 av = *(const f16x8*)(ap + mf * 16384 + kt * 32);
      acc[mf] = mfma16x32(av, bv[kt], acc[mf]);
    }
  }

  // dump per-wave partials: D frag row = mf*16 + kg*4 + r, col = j
#pragma unroll
  for (int mf = 0; mf < 4; ++mf)
#pragma unroll
    for (int r = 0; r < 4; ++r)
      zred[w * 1024 + (mf * 16 + kg * 4 + r) * 16 + j] = acc[mf][r];
  __syncthreads();

  // epilogue: one thread per (batch row, unit-within-WG)
  const int row = tid & 63, uu = tid >> 6;
  const int u = u0 + uu;
  const f16* xrow = XZ + (size_t)(t * 64 + row) * 4096;
  float z[4];
#pragma unroll
  for (int g = 0; g < 4; ++g) {
    float s = (float)xrow[g * 1024 + u];
#pragma unroll
    for (int wv = 0; wv < 4; ++wv)
      s += zred[wv * 1024 + row * 16 + g * 4 + uu];
    z[g] = s;
  }
  float gi = sigmoidf_(z[0]);
  float gf = sigmoidf_(z[1]);
  float gg = tanhf(z[2]);
  float go = sigmoidf_(z[3]);
  float cn = gf * cst[row * 1024 + u] + gi * gg;
  float hn = go * tanhf(cn);
  cst[row * 1024 + u] = cn;
  hout[row * 1024 + u] = (f16)hn;
  if (A1) A1[(size_t)(t * 64 + row) * 1024 + u] = (f16)hn;       // layer-1 input
  if (outx) outx[(size_t)row * 262144 + (size_t)t * 1024 + u] = hn;
  if (outh) {
    outh[row * 1024 + u] = hn;
    outc[row * 1024 + u] = cn;
  }
}

extern "C" void kernel_launch(void* const* d_in, const int* in_sizes, int n_in,
                              void* d_out, int out_size, void* d_ws, size_t ws_size,
                              hipStream_t stream) {
  (void)in_sizes; (void)n_in; (void)out_size; (void)ws_size;
  const int* tokens = (const int*)d_in[0];
  const float* emb = (const float*)d_in[1];
  const float* W0 = (const float*)d_in[2];
  const float* U0 = (const float*)d_in[3];
  const float* b0 = (const float*)d_in[4];
  const float* W1 = (const float*)d_in[5];
  const float* U1 = (const float*)d_in[6];
  const float* b1 = (const float*)d_in[7];
  float* out = (float*)d_out;

  // workspace carve-up (~205 MiB)
  char* p = (char*)d_ws;
  f16* A0 = (f16*)p;   p += (size_t)16384 * 512 * 2;    // x tokens, fp16
  f16* A1 = (f16*)p;   p += (size_t)16384 * 1024 * 2;   // layer0 outputs, fp16
  f16* W0t = (f16*)p;  p += (size_t)4096 * 512 * 2;     // W0^T
  f16* U0t = (f16*)p;  p += (size_t)4096 * 1024 * 2;    // U0^T
  f16* W1t = (f16*)p;  p += (size_t)4096 * 1024 * 2;    // W1^T
  f16* U1t = (f16*)p;  p += (size_t)4096 * 1024 * 2;    // U1^T
  f16* XZ = (f16*)p;   p += (size_t)16384 * 4096 * 2;   // xz, rows t*64+b
  f16* Ha = (f16*)p;   p += 64 * 1024 * 2;              // h ping
  f16* Hb = (f16*)p;   p += 64 * 1024 * 2;              // h pong
  float* Cst = (float*)p; p += 64 * 1024 * 4;           // c state (f32)

  // weight transposes + casts
  k_transpose_f16<<<512, 256, 0, stream>>>(W0, W0t, 512, 4096);
  k_transpose_f16<<<1024, 256, 0, stream>>>(U0, U0t, 1024, 4096);
  k_transpose_f16<<<1024, 256, 0, stream>>>(W1, W1t, 1024, 4096);
  k_transpose_f16<<<1024, 256, 0, stream>>>(U1, U1t, 1024, 4096);

  // embedding
  k_embed_f16<<<8192, 256, 0, stream>>>(tokens, emb, A0);

  // layer 0: xz0 = x @ W0 + b0
  k_gemm_f16<<<4096, 256, 0, stream>>>(A0, W0t, b0, XZ, 16384, 4096, 512);
  hipMemsetAsync(Ha, 0, 64 * 1024 * 2, stream);
  hipMemsetAsync(Cst, 0, 64 * 1024 * 4, stream);
  for (int t = 0; t < 256; ++t) {
    const f16* hi = (t & 1) ? Hb : Ha;
    f16* ho = (t & 1) ? Ha : Hb;
    k_lstm_step<<<256, 256, 0, stream>>>(XZ, U0t, hi, ho, Cst, A1,
                                         nullptr, nullptr, nullptr, t);
  }

  // layer 1: xz1 = ys0 @ W1 + b1
  k_gemm_f16<<<4096, 256, 0, stream>>>(A1, W1t, b1, XZ, 16384, 4096, 1024);
  hipMemsetAsync(Ha, 0, 64 * 1024 * 2, stream);
  hipMemsetAsync(Cst, 0, 64 * 1024 * 4, stream);
  for (int t = 0; t < 256; ++t) {
    const f16* hi = (t & 1) ? Hb : Ha;
    f16* ho = (t & 1) ? Ha : Hb;
    k_lstm_step<<<256, 256, 0, stream>>>(XZ, U1t, hi, ho, Cst, nullptr,
                                         out,
                                         (t == 255) ? (out + 16777216) : nullptr,
                                         (t == 255) ? (out + 16777216 + 65536) : nullptr,
                                         t);
  }
}